// Round 8
// baseline (1571.350 us; speedup 1.0000x reference)
//
#include <hip/hip_runtime.h>
#include <cstddef>

#define NN 100000
#define NE 800000
#define DD 256

typedef unsigned short u16;
typedef unsigned char u8;
typedef __bf16 bf8_t __attribute__((ext_vector_type(8)));
typedef float f32x4 __attribute__((ext_vector_type(4)));

__device__ __forceinline__ float bf2f(u16 u) {
    union { unsigned int i; float f; } v; v.i = ((unsigned int)u) << 16; return v.f;
}
__device__ __forceinline__ u16 f2bf(float f) {
    union { float f; unsigned int i; } v; v.f = f;
    unsigned int x = v.i;
    unsigned int r = (x + 0x7FFFu + ((x >> 16) & 1u)) >> 16;
    return (u16)r;
}

template <int F32>
__device__ __forceinline__ float LD(const void* p, int i) {
    if (F32) return ((const float*)p)[i];
    return bf2f(((const u16*)p)[i]);
}

template <int F32>
__device__ __forceinline__ bf8_t LDB(const void* W, int off) {
    if (!F32) return *(const bf8_t*)((const u16*)W + off);
    const float4* p = (const float4*)((const float*)W + off);
    float4 lo = p[0], hi = p[1];
    bf8_t r;
    r[0] = (__bf16)lo.x; r[1] = (__bf16)lo.y; r[2] = (__bf16)lo.z; r[3] = (__bf16)lo.w;
    r[4] = (__bf16)hi.x; r[5] = (__bf16)hi.y; r[6] = (__bf16)hi.z; r[7] = (__bf16)hi.w;
    return r;
}

__global__ void GNNActor_23192823398472_kernel() {}

// ---- prep: zero cnt_i+cursor, compute dtype flags (block 0 wave 0) ----
__global__ void k_prep(const u16* __restrict__ x, const int* __restrict__ ei,
                       int* __restrict__ flags, int* __restrict__ zbase, int nz) {
    int i = blockIdx.x * blockDim.x + threadIdx.x;
    if (i < nz) zbase[i] = 0;
    if (blockIdx.x == 0 && threadIdx.x < 64) {
        int lane = threadIdx.x;
        int big = 0;
        for (int k = lane; k < 4096; k += 64) {
            u16 u = x[k];
            if (((u >> 7) & 0xFF) >= 140) ++big;
        }
        #pragma unroll
        for (int off = 32; off; off >>= 1) big += __shfl_down(big, off, 64);
        int bad = 0;
        for (int k = lane; k < 128; k += 64) bad |= (ei[2 * k + 1] != 0) ? 1 : 0;
        unsigned long long anybad = __ballot(bad);
        if (lane == 0) {
            flags[0] = (big > 64) ? 1 : 0;   // f32 inputs iff wild bf16 exponents
            flags[1] = anybad ? 0 : 1;       // int64 iff odd int32 slots all zero
        }
    }
}

__device__ __forceinline__ int ld_dst(const int* ei, int e, int i64) {
    return i64 ? ei[2 * (NE + e)] : ei[NE + e];
}
__device__ __forceinline__ int ld_src(const int* ei, int e, int i64) {
    return i64 ? ei[2 * e] : ei[e];
}

__global__ void k_hist(const int* __restrict__ ei, int* __restrict__ cnt_i,
                       const int* __restrict__ flags) {
    int e = blockIdx.x * blockDim.x + threadIdx.x;
    if (e >= NE) return;
    atomicAdd(&cnt_i[ld_dst(ei, e, flags[1])], 1);
}

// single-launch exclusive scan: 1024 threads x 98-element chunks
__global__ void k_scan(const int* __restrict__ cnt_i, int* __restrict__ row_start) {
    __shared__ int part[1024];
    const int C = 98;
    int t = threadIdx.x;
    int base = t * C;
    int sum = 0;
    for (int j = 0; j < C; ++j) {
        int i = base + j;
        if (i < NN) sum += cnt_i[i];
    }
    part[t] = sum;
    __syncthreads();
    for (int off = 1; off < 1024; off <<= 1) {
        int add = (t >= off) ? part[t - off] : 0;
        __syncthreads();
        part[t] += add;
        __syncthreads();
    }
    int run = part[t] - sum;
    for (int j = 0; j < C; ++j) {
        int i = base + j;
        if (i < NN) { row_start[i] = run; run += cnt_i[i]; }
    }
    if (t == 0) row_start[NN] = NE;
}

__global__ void k_fill(const int* __restrict__ ei, const int* __restrict__ row_start,
                       int* __restrict__ cursor, int* __restrict__ elist,
                       const int* __restrict__ flags) {
    int e = blockIdx.x * blockDim.x + threadIdx.x;
    if (e >= NE) return;
    int i64 = flags[1];
    int dst = ld_dst(ei, e, i64);
    int pos = atomicAdd(&cursor[dst], 1);
    elist[row_start[dst] + pos] = ld_src(ei, e, i64);
}

// ---------------- fused: edge-parallel LDS-atomic gather + MFMA net ----------------
// LDS map (53248 B + s_rs):
//   [0,33280)      s_agg f32 32x260 planar (gather)  -> then s_mean bf16 32x264 [0,16896)
//   [16896,33792)  s_h bf16 32x264 (conv out; overlaps dead s_agg upper half)
//   [33792,50688)  s_x bf16 32x264 (staged x; residual) -> then s_h1 [33792,42496), s_h2 [42496,45056)
//   [50688,52736)  s_el 512 ints (block CSR slice)
//   [52736,53248)  s_row 512 u8 (edge -> block-local node)
// Planar agg addr = row*260 + plane*64 + lane -> bank = lane&31 (2-way, free).

#define LOADG(J, U, F, R, M)                                                        \
    _Pragma("unroll") for (int g = 0; g < 4; ++g) {                                 \
        int e_ = (J) + g; int ok_ = e_ < b1 ? 1 : 0; int ee_ = ok_ ? e_ : b0;       \
        R[g] = s_row[ee_]; M[g] = ok_ ? 1.f : 0.f;                                  \
        int src_ = s_el[ee_];                                                       \
        if (F32) F[g] = *(const float4*)((const float*)xv + (size_t)src_ * DD + (lane << 2)); \
        else     U[g] = *(const ushort4*)((const u16*)xv + (size_t)src_ * DD + (lane << 2));  \
    }

#define ADDG(U, F, R, M)                                                            \
    _Pragma("unroll") for (int g = 0; g < 4; ++g) {                                 \
        float v0_, v1_, v2_, v3_;                                                   \
        if (F32) { v0_ = F[g].x; v1_ = F[g].y; v2_ = F[g].z; v3_ = F[g].w; }        \
        else { v0_ = bf2f(U[g].x); v1_ = bf2f(U[g].y); v2_ = bf2f(U[g].z); v3_ = bf2f(U[g].w); } \
        float* b_ = s_agg + R[g] * 260 + lane; float m_ = M[g];                     \
        atomicAdd(b_,       v0_ * m_);                                              \
        atomicAdd(b_ + 64,  v1_ * m_);                                              \
        atomicAdd(b_ + 128, v2_ * m_);                                              \
        atomicAdd(b_ + 192, v3_ * m_);                                              \
    }

template <int F32>
__device__ __forceinline__ void fused_body(
        const int* __restrict__ row_start, const int* __restrict__ elist,
        const void* __restrict__ xv,
        const void* __restrict__ Wl, const void* __restrict__ bl,
        const void* __restrict__ Wr,
        const void* __restrict__ W1, const void* __restrict__ b1,
        const void* __restrict__ W2, const void* __restrict__ b2,
        const void* __restrict__ W3, const void* __restrict__ b3,
        void* __restrict__ outv, char* smem, int* s_rs) {
    float* s_agg = (float*)smem;
    u16* s_mean  = (u16*)smem;
    u16* s_h     = (u16*)(smem + 16896);
    u16* s_x     = (u16*)(smem + 33792);
    u16* s_h1    = (u16*)(smem + 33792);
    u16* s_h2    = (u16*)(smem + 42496);
    int* s_el    = (int*)(smem + 50688);
    u8*  s_row   = (u8*)(smem + 52736);

    int t = threadIdx.x;
    int node0 = blockIdx.x * 32;
    int wv = t >> 6, lane = t & 63;

    if (t < 33) s_rs[t] = row_start[node0 + t];

    for (int i = t; i < 32 * 260; i += 256) s_agg[i] = 0.f;

    // stage x -> s_x (stride 264)
    if (F32) {
        for (int i = t; i < 32 * 64; i += 256) {
            int row = i >> 6, k4 = (i & 63) << 2;
            float4 f = *(const float4*)((const float*)xv + (size_t)(node0 + row) * DD + k4);
            ushort4 u;
            u.x = f2bf(f.x); u.y = f2bf(f.y); u.z = f2bf(f.z); u.w = f2bf(f.w);
            *(ushort4*)&s_x[row * 264 + k4] = u;
        }
    } else {
        for (int i = t; i < 32 * 64; i += 256) {
            int row = i >> 6, k4 = (i & 63) << 2;
            *(ushort4*)&s_x[row * 264 + k4] =
                *(const ushort4*)((const u16*)xv + (size_t)(node0 + row) * DD + k4);
        }
    }
    __syncthreads();

    int rs0 = s_rs[0];
    int ne = s_rs[32] - rs0;

    for (int base = 0; base < ne; base += 512) {
        int nc = ne - base; if (nc > 512) nc = 512;
        for (int i = t; i < nc; i += 256) s_el[i] = elist[rs0 + base + i];
        if (t < 32) {
            int st = s_rs[t] - rs0 - base;     if (st < 0) st = 0;
            int en = s_rs[t + 1] - rs0 - base; if (en > nc) en = nc;
            for (int e = st; e < en; ++e) s_row[e] = (u8)t;
        }
        __syncthreads();

        int per = (nc + 3) >> 2;
        int b0 = wv * per;
        int b1 = b0 + per; if (b1 > nc) b1 = nc;
        if (b0 < b1) {
            int ng = (b1 - b0 + 3) >> 2;
            ushort4 uA[4], uB[4]; float4 fA[4], fB[4];
            int rA[4], rB[4]; float mA[4], mB[4];
            LOADG(b0, uA, fA, rA, mA);
            for (int k = 1; k < ng; ++k) {
                LOADG(b0 + k * 4, uB, fB, rB, mB);
                ADDG(uA, fA, rA, mA);
                #pragma unroll
                for (int g = 0; g < 4; ++g) {
                    uA[g] = uB[g]; fA[g] = fB[g]; rA[g] = rB[g]; mA[g] = mB[g];
                }
            }
            ADDG(uA, fA, rA, mA);
        }
        __syncthreads();
    }

    // convert planar f32 agg -> bf16 mean (regs + barrier; s_mean overlaps s_agg)
    {
        int r = t >> 3, c0 = (t & 7) * 32;
        float inv = 1.f / fmaxf((float)(s_rs[r + 1] - s_rs[r]), 1.f);
        float vals[32];
        #pragma unroll
        for (int cc = 0; cc < 32; ++cc) {
            int c = c0 + cc;
            vals[cc] = s_agg[r * 260 + (c & 3) * 64 + (c >> 2)] * inv;
        }
        __syncthreads();
        #pragma unroll
        for (int cc = 0; cc < 32; cc += 4) {
            ushort4 o;
            o.x = f2bf(vals[cc]);     o.y = f2bf(vals[cc + 1]);
            o.z = f2bf(vals[cc + 2]); o.w = f2bf(vals[cc + 3]);
            *(ushort4*)&s_mean[r * 264 + c0 + cc] = o;
        }
    }
    __syncthreads();

    int lq = lane >> 4, lr = lane & 15;

    // ---- conv: [32 x 512] @ B(512,256); K-chunks 0-7 from s_mean/Wl, 8-15 from s_x/Wr ----
    f32x4 acc[2][4];
    #pragma unroll
    for (int rt = 0; rt < 2; ++rt)
        #pragma unroll
        for (int ct = 0; ct < 4; ++ct) acc[rt][ct] = (f32x4){0.f, 0.f, 0.f, 0.f};

    for (int c = 0; c < 16; ++c) {
        const u16* pa0 = (c < 8) ? &s_mean[lr * 264 + c * 32 + lq * 8]
                                 : &s_x[lr * 264 + (c - 8) * 32 + lq * 8];
        const u16* pa1 = (c < 8) ? &s_mean[(16 + lr) * 264 + c * 32 + lq * 8]
                                 : &s_x[(16 + lr) * 264 + (c - 8) * 32 + lq * 8];
        bf8_t a0 = *(const bf8_t*)pa0;
        bf8_t a1 = *(const bf8_t*)pa1;
        #pragma unroll
        for (int ct = 0; ct < 4; ++ct) {
            int n = (wv * 4 + ct) * 16 + lr;
            bf8_t b = (c < 8) ? LDB<F32>(Wl, n * DD + c * 32 + lq * 8)
                              : LDB<F32>(Wr, n * DD + (c - 8) * 32 + lq * 8);
            acc[0][ct] = __builtin_amdgcn_mfma_f32_16x16x32_bf16(a0, b, acc[0][ct], 0, 0, 0);
            acc[1][ct] = __builtin_amdgcn_mfma_f32_16x16x32_bf16(a1, b, acc[1][ct], 0, 0, 0);
        }
    }
    #pragma unroll
    for (int ct = 0; ct < 4; ++ct) {
        int n = (wv * 4 + ct) * 16 + lr;
        float bb = LD<F32>(bl, n);
        #pragma unroll
        for (int rt = 0; rt < 2; ++rt)
            #pragma unroll
            for (int i = 0; i < 4; ++i) {
                int m = rt * 16 + lq * 4 + i;
                float v = acc[rt][ct][i] + bb;
                v = fmaxf(v, 0.f) + bf2f(s_x[m * 264 + n]);
                s_h[m * 264 + n] = f2bf(v);
            }
    }
    __syncthreads();   // s_x dead -> s_h1/s_h2 alias it

    // ---- layer1: [32,256] @ W1^T(256,128) ----
    {
        f32x4 a1c[2][2];
        #pragma unroll
        for (int rt = 0; rt < 2; ++rt)
            #pragma unroll
            for (int ct = 0; ct < 2; ++ct) a1c[rt][ct] = (f32x4){0.f, 0.f, 0.f, 0.f};
        for (int c = 0; c < 8; ++c) {
            bf8_t a0 = *(const bf8_t*)&s_h[lr * 264 + c * 32 + lq * 8];
            bf8_t a1 = *(const bf8_t*)&s_h[(16 + lr) * 264 + c * 32 + lq * 8];
            #pragma unroll
            for (int ct = 0; ct < 2; ++ct) {
                int n = (wv * 2 + ct) * 16 + lr;
                bf8_t b = LDB<F32>(W1, n * DD + c * 32 + lq * 8);
                a1c[0][ct] = __builtin_amdgcn_mfma_f32_16x16x32_bf16(a0, b, a1c[0][ct], 0, 0, 0);
                a1c[1][ct] = __builtin_amdgcn_mfma_f32_16x16x32_bf16(a1, b, a1c[1][ct], 0, 0, 0);
            }
        }
        #pragma unroll
        for (int ct = 0; ct < 2; ++ct) {
            int n = (wv * 2 + ct) * 16 + lr;
            float bb = LD<F32>(b1, n);
            #pragma unroll
            for (int rt = 0; rt < 2; ++rt)
                #pragma unroll
                for (int i = 0; i < 4; ++i) {
                    int m = rt * 16 + lq * 4 + i;
                    s_h1[m * 136 + n] = f2bf(fmaxf(a1c[rt][ct][i] + bb, 0.f));
                }
        }
    }
    __syncthreads();

    // ---- layer2: [32,128] @ W2^T(128,32), waves 0,1 ----
    if (wv < 2) {
        f32x4 a2c[2];
        a2c[0] = (f32x4){0.f, 0.f, 0.f, 0.f};
        a2c[1] = (f32x4){0.f, 0.f, 0.f, 0.f};
        int n = wv * 16 + lr;
        for (int c = 0; c < 4; ++c) {
            bf8_t a0 = *(const bf8_t*)&s_h1[lr * 136 + c * 32 + lq * 8];
            bf8_t a1 = *(const bf8_t*)&s_h1[(16 + lr) * 136 + c * 32 + lq * 8];
            bf8_t b = LDB<F32>(W2, n * 128 + c * 32 + lq * 8);
            a2c[0] = __builtin_amdgcn_mfma_f32_16x16x32_bf16(a0, b, a2c[0], 0, 0, 0);
            a2c[1] = __builtin_amdgcn_mfma_f32_16x16x32_bf16(a1, b, a2c[1], 0, 0, 0);
        }
        float bb = LD<F32>(b2, n);
        #pragma unroll
        for (int rt = 0; rt < 2; ++rt)
            #pragma unroll
            for (int i = 0; i < 4; ++i) {
                int m = rt * 16 + lq * 4 + i;
                s_h2[m * 40 + n] = f2bf(fmaxf(a2c[rt][i] + bb, 0.f));
            }
    }
    __syncthreads();

    // ---- layer3 ----
    if (t < 32) {
        float a3 = LD<F32>(b3, 0);
        #pragma unroll
        for (int k = 0; k < 32; ++k)
            a3 += bf2f(s_h2[t * 40 + k]) * LD<F32>(W3, k);
        if (F32) ((float*)outv)[node0 + t] = a3;
        else     ((u16*)outv)[node0 + t]   = f2bf(a3);
    }
}

__launch_bounds__(256)
__global__ void k_fused(const int* __restrict__ row_start, const int* __restrict__ elist,
                        const void* __restrict__ xv,
                        const void* __restrict__ Wl, const void* __restrict__ bl,
                        const void* __restrict__ Wr,
                        const void* __restrict__ W1, const void* __restrict__ b1,
                        const void* __restrict__ W2, const void* __restrict__ b2,
                        const void* __restrict__ W3, const void* __restrict__ b3,
                        void* __restrict__ outv, const int* __restrict__ flags) {
    __shared__ __align__(16) char smem[53248];
    __shared__ int s_rs[33];
    if (flags[0])
        fused_body<1>(row_start, elist, xv, Wl, bl, Wr, W1, b1, W2, b2, W3, b3, outv, smem, s_rs);
    else
        fused_body<0>(row_start, elist, xv, Wl, bl, Wr, W1, b1, W2, b2, W3, b3, outv, smem, s_rs);
}

extern "C" void kernel_launch(void* const* d_in, const int* in_sizes, int n_in,
                              void* d_out, int out_size, void* d_ws, size_t ws_size,
                              hipStream_t stream) {
    const u16* x  = (const u16*)d_in[0];
    const int* ei = (const int*)d_in[1];
    const void* Wl = d_in[2];
    const void* bl = d_in[3];
    const void* Wr = d_in[4];
    const void* W1 = d_in[5];
    const void* b1 = d_in[6];
    const void* W2 = d_in[7];
    const void* b2 = d_in[8];
    const void* W3 = d_in[9];
    const void* b3 = d_in[10];

    // ws (ints): [flags 2][pad 256][cnt_i NN][cursor NN][row_start NN+1][elist NE]
    int* flags     = (int*)d_ws;
    int* cnt_i     = flags + 256;
    int* cursor    = cnt_i + NN;
    int* row_start = cursor + NN;
    int* elist     = row_start + NN + 1;

    k_prep<<<(2 * NN + 255) / 256, 256, 0, stream>>>(x, ei, flags, cnt_i, 2 * NN);
    k_hist<<<(NE + 255) / 256, 256, 0, stream>>>(ei, cnt_i, flags);
    k_scan<<<1, 1024, 0, stream>>>(cnt_i, row_start);
    k_fill<<<(NE + 255) / 256, 256, 0, stream>>>(ei, row_start, cursor, elist, flags);
    k_fused<<<NN / 32, 256, 0, stream>>>(row_start, elist, (const void*)x, Wl, bl, Wr,
                                         W1, b1, W2, b2, W3, b3, d_out, flags);
}

// Round 9
// 727.952 us; speedup vs baseline: 2.1586x; 2.1586x over previous
//
#include <hip/hip_runtime.h>
#include <cstddef>

#define NN 100000
#define NE 800000
#define DD 256

typedef unsigned short u16;
typedef __bf16 bf8_t __attribute__((ext_vector_type(8)));
typedef float f32x4 __attribute__((ext_vector_type(4)));

__device__ __forceinline__ float bf2f(u16 u) {
    union { unsigned int i; float f; } v; v.i = ((unsigned int)u) << 16; return v.f;
}
__device__ __forceinline__ u16 f2bf(float f) {
    union { float f; unsigned int i; } v; v.f = f;
    unsigned int x = v.i;
    unsigned int r = (x + 0x7FFFu + ((x >> 16) & 1u)) >> 16;
    return (u16)r;
}

template <int F32>
__device__ __forceinline__ float LD(const void* p, int i) {
    if (F32) return ((const float*)p)[i];
    return bf2f(((const u16*)p)[i]);
}

template <int F32>
__device__ __forceinline__ bf8_t LDB(const void* W, int off) {
    if (!F32) return *(const bf8_t*)((const u16*)W + off);
    const float4* p = (const float4*)((const float*)W + off);
    float4 lo = p[0], hi = p[1];
    bf8_t r;
    r[0] = (__bf16)lo.x; r[1] = (__bf16)lo.y; r[2] = (__bf16)lo.z; r[3] = (__bf16)lo.w;
    r[4] = (__bf16)hi.x; r[5] = (__bf16)hi.y; r[6] = (__bf16)hi.z; r[7] = (__bf16)hi.w;
    return r;
}

__global__ void GNNActor_23192823398472_kernel() {}

// ---- prep: zero cnt_i+cursor, compute dtype flags (block 0 wave 0) ----
__global__ void k_prep(const u16* __restrict__ x, const int* __restrict__ ei,
                       int* __restrict__ flags, int* __restrict__ zbase, int nz) {
    int i = blockIdx.x * blockDim.x + threadIdx.x;
    if (i < nz) zbase[i] = 0;
    if (blockIdx.x == 0 && threadIdx.x < 64) {
        int lane = threadIdx.x;
        int big = 0;
        for (int k = lane; k < 4096; k += 64) {
            u16 u = x[k];
            if (((u >> 7) & 0xFF) >= 140) ++big;
        }
        #pragma unroll
        for (int off = 32; off; off >>= 1) big += __shfl_down(big, off, 64);
        int bad = 0;
        for (int k = lane; k < 128; k += 64) bad |= (ei[2 * k + 1] != 0) ? 1 : 0;
        unsigned long long anybad = __ballot(bad);
        if (lane == 0) {
            flags[0] = (big > 64) ? 1 : 0;   // f32 inputs iff wild bf16 exponents
            flags[1] = anybad ? 0 : 1;       // int64 iff odd int32 slots all zero
        }
    }
}

__device__ __forceinline__ int ld_dst(const int* ei, int e, int i64) {
    return i64 ? ei[2 * (NE + e)] : ei[NE + e];
}
__device__ __forceinline__ int ld_src(const int* ei, int e, int i64) {
    return i64 ? ei[2 * e] : ei[e];
}

__global__ void k_hist(const int* __restrict__ ei, int* __restrict__ cnt_i,
                       const int* __restrict__ flags) {
    int e = blockIdx.x * blockDim.x + threadIdx.x;
    if (e >= NE) return;
    atomicAdd(&cnt_i[ld_dst(ei, e, flags[1])], 1);
}

// single-launch exclusive scan: 1024 threads x 98-element chunks
__global__ void k_scan(const int* __restrict__ cnt_i, int* __restrict__ row_start) {
    __shared__ int part[1024];
    const int C = 98;
    int t = threadIdx.x;
    int base = t * C;
    int sum = 0;
    for (int j = 0; j < C; ++j) {
        int i = base + j;
        if (i < NN) sum += cnt_i[i];
    }
    part[t] = sum;
    __syncthreads();
    for (int off = 1; off < 1024; off <<= 1) {
        int add = (t >= off) ? part[t - off] : 0;
        __syncthreads();
        part[t] += add;
        __syncthreads();
    }
    int run = part[t] - sum;
    for (int j = 0; j < C; ++j) {
        int i = base + j;
        if (i < NN) { row_start[i] = run; run += cnt_i[i]; }
    }
    if (t == 0) row_start[NN] = NE;
}

__global__ void k_fill(const int* __restrict__ ei, const int* __restrict__ row_start,
                       int* __restrict__ cursor, int* __restrict__ elist,
                       const int* __restrict__ flags) {
    int e = blockIdx.x * blockDim.x + threadIdx.x;
    if (e >= NE) return;
    int i64 = flags[1];
    int dst = ld_dst(ei, e, i64);
    int pos = atomicAdd(&cursor[dst], 1);
    elist[row_start[dst] + pos] = ld_src(ei, e, i64);
}

// ---------------- MFMA fused gather + conv + residual + MLP ----------------
// R7 structure (register-accum gather; R8's LDS-atomic variant was a 3.3x
// regression: 3.2M ds_add_f32 RMWs + vmcnt(0)-serialized pipeline). Changes:
// 512 threads (8 waves, 4 nodes/wave), 8-wide masked unroll (8 outstanding
// 512B row loads/wave), block elist slice staged in LDS.
// LDS map (52224 B): s_a u16 32x520 [mean|x] @0 (33280); s_h u16 32x264
// @33280 (16896); s_el int[512] @50176; h1 @0 (8704) / h2 @20480 (2560)
// alias dead s_a after conv.
#define SA 520
#define SH 264
#define SH1 136
#define SH2 40
template <int F32>
__device__ __forceinline__ void fused_body(
        const int* __restrict__ row_start, const int* __restrict__ elist,
        const void* __restrict__ xv,
        const void* __restrict__ Wl, const void* __restrict__ bl,
        const void* __restrict__ Wr,
        const void* __restrict__ W1, const void* __restrict__ b1,
        const void* __restrict__ W2, const void* __restrict__ b2,
        const void* __restrict__ W3, const void* __restrict__ b3,
        void* __restrict__ outv, char* smem, int* s_rs) {
    u16* s_a  = (u16*)smem;
    u16* s_h  = (u16*)(smem + 33280);
    u16* s_h1 = (u16*)smem;
    u16* s_h2 = (u16*)(smem + 20480);
    int* s_el = (int*)(smem + 50176);

    int t = threadIdx.x;
    int node0 = blockIdx.x * 32;
    int wv = t >> 6, lane = t & 63;

    if (t < 33) s_rs[t] = row_start[node0 + t];

    // stage x -> s_a[.. 256..511]
    if (F32) {
        for (int i = t; i < 32 * 64; i += 512) {
            int row = i >> 6, k4 = (i & 63) << 2;
            float4 f = *(const float4*)((const float*)xv + (size_t)(node0 + row) * DD + k4);
            ushort4 u;
            u.x = f2bf(f.x); u.y = f2bf(f.y); u.z = f2bf(f.z); u.w = f2bf(f.w);
            *(ushort4*)&s_a[row * SA + 256 + k4] = u;
        }
    } else {
        for (int i = t; i < 32 * 64; i += 512) {
            int row = i >> 6, k4 = (i & 63) << 2;
            *(ushort4*)&s_a[row * SA + 256 + k4] =
                *(const ushort4*)((const u16*)xv + (size_t)(node0 + row) * DD + k4);
        }
    }
    __syncthreads();   // s_rs valid

    int rs0 = s_rs[0];
    int ne = s_rs[32] - rs0;
    {
        int lim = ne < 512 ? ne : 512;
        for (int i = t; i < lim; i += 512) s_el[i] = elist[rs0 + i];
    }
    __syncthreads();

    // gather + mean -> s_a[.. 0..255]; 8-wide masked unroll, wave-uniform ctl
    for (int i = 0; i < 4; ++i) {
        int ni = wv * 4 + i;
        int rs = s_rs[ni], re = s_rs[ni + 1];
        float a0 = 0.f, a1 = 0.f, a2 = 0.f, a3 = 0.f;
        for (int e = rs; e < re; e += 8) {
            ushort4 u[8]; float4 f[8]; float m[8];
            #pragma unroll
            for (int g = 0; g < 8; ++g) {
                int eg = e + g;
                int ok = eg < re;
                int idx = ok ? eg : rs;
                m[g] = ok ? 1.f : 0.f;
                int j = idx - rs0;
                int src = (j < 512) ? s_el[j] : elist[idx];
                if (F32) f[g] = *(const float4*)((const float*)xv + (size_t)src * DD + (lane << 2));
                else     u[g] = *(const ushort4*)((const u16*)xv + (size_t)src * DD + (lane << 2));
            }
            #pragma unroll
            for (int g = 0; g < 8; ++g) {
                if (F32) {
                    a0 = fmaf(m[g], f[g].x, a0); a1 = fmaf(m[g], f[g].y, a1);
                    a2 = fmaf(m[g], f[g].z, a2); a3 = fmaf(m[g], f[g].w, a3);
                } else {
                    a0 = fmaf(m[g], bf2f(u[g].x), a0); a1 = fmaf(m[g], bf2f(u[g].y), a1);
                    a2 = fmaf(m[g], bf2f(u[g].z), a2); a3 = fmaf(m[g], bf2f(u[g].w), a3);
                }
            }
        }
        float inv = 1.f / fmaxf((float)(re - rs), 1.f);
        ushort4 o;
        o.x = f2bf(a0 * inv); o.y = f2bf(a1 * inv);
        o.z = f2bf(a2 * inv); o.w = f2bf(a3 * inv);
        *(ushort4*)&s_a[ni * SA + (lane << 2)] = o;
    }
    __syncthreads();

    int lq = lane >> 4, lr = lane & 15;

    // ---- conv: [32,512] @ B(512,256); 8 waves x 2 col-tiles ----
    f32x4 acc[2][2];
    #pragma unroll
    for (int rt = 0; rt < 2; ++rt)
        #pragma unroll
        for (int ct = 0; ct < 2; ++ct) acc[rt][ct] = (f32x4){0.f, 0.f, 0.f, 0.f};

    for (int c = 0; c < 16; ++c) {
        bf8_t a0 = *(const bf8_t*)&s_a[lr * SA + c * 32 + lq * 8];
        bf8_t a1 = *(const bf8_t*)&s_a[(16 + lr) * SA + c * 32 + lq * 8];
        #pragma unroll
        for (int ct = 0; ct < 2; ++ct) {
            int n = (wv * 2 + ct) * 16 + lr;
            bf8_t b = (c < 8) ? LDB<F32>(Wl, n * DD + c * 32 + lq * 8)
                              : LDB<F32>(Wr, n * DD + (c - 8) * 32 + lq * 8);
            acc[0][ct] = __builtin_amdgcn_mfma_f32_16x16x32_bf16(a0, b, acc[0][ct], 0, 0, 0);
            acc[1][ct] = __builtin_amdgcn_mfma_f32_16x16x32_bf16(a1, b, acc[1][ct], 0, 0, 0);
        }
    }
    #pragma unroll
    for (int ct = 0; ct < 2; ++ct) {
        int n = (wv * 2 + ct) * 16 + lr;
        float bb = LD<F32>(bl, n);
        #pragma unroll
        for (int rt = 0; rt < 2; ++rt)
            #pragma unroll
            for (int i = 0; i < 4; ++i) {
                int m = rt * 16 + lq * 4 + i;
                float v = acc[rt][ct][i] + bb;
                v = fmaxf(v, 0.f) + bf2f(s_a[m * SA + 256 + n]);
                s_h[m * SH + n] = f2bf(v);
            }
    }
    __syncthreads();   // s_a dead -> s_h1/s_h2 alias it

    // ---- layer1: [32,256] @ W1^T(256,128); 8 waves x 1 col-tile ----
    {
        f32x4 a1c[2];
        a1c[0] = (f32x4){0.f, 0.f, 0.f, 0.f};
        a1c[1] = (f32x4){0.f, 0.f, 0.f, 0.f};
        int n = wv * 16 + lr;
        for (int c = 0; c < 8; ++c) {
            bf8_t a0 = *(const bf8_t*)&s_h[lr * SH + c * 32 + lq * 8];
            bf8_t a1 = *(const bf8_t*)&s_h[(16 + lr) * SH + c * 32 + lq * 8];
            bf8_t b = LDB<F32>(W1, n * DD + c * 32 + lq * 8);
            a1c[0] = __builtin_amdgcn_mfma_f32_16x16x32_bf16(a0, b, a1c[0], 0, 0, 0);
            a1c[1] = __builtin_amdgcn_mfma_f32_16x16x32_bf16(a1, b, a1c[1], 0, 0, 0);
        }
        float bb = LD<F32>(b1, n);
        #pragma unroll
        for (int rt = 0; rt < 2; ++rt)
            #pragma unroll
            for (int i = 0; i < 4; ++i) {
                int m = rt * 16 + lq * 4 + i;
                s_h1[m * SH1 + n] = f2bf(fmaxf(a1c[rt][i] + bb, 0.f));
            }
    }
    __syncthreads();

    // ---- layer2: [32,128] @ W2^T(128,32); waves 0,1 ----
    if (wv < 2) {
        f32x4 a2c[2];
        a2c[0] = (f32x4){0.f, 0.f, 0.f, 0.f};
        a2c[1] = (f32x4){0.f, 0.f, 0.f, 0.f};
        int n = wv * 16 + lr;
        for (int c = 0; c < 4; ++c) {
            bf8_t a0 = *(const bf8_t*)&s_h1[lr * SH1 + c * 32 + lq * 8];
            bf8_t a1 = *(const bf8_t*)&s_h1[(16 + lr) * SH1 + c * 32 + lq * 8];
            bf8_t b = LDB<F32>(W2, n * 128 + c * 32 + lq * 8);
            a2c[0] = __builtin_amdgcn_mfma_f32_16x16x32_bf16(a0, b, a2c[0], 0, 0, 0);
            a2c[1] = __builtin_amdgcn_mfma_f32_16x16x32_bf16(a1, b, a2c[1], 0, 0, 0);
        }
        float bb = LD<F32>(b2, n);
        #pragma unroll
        for (int rt = 0; rt < 2; ++rt)
            #pragma unroll
            for (int i = 0; i < 4; ++i) {
                int m = rt * 16 + lq * 4 + i;
                s_h2[m * SH2 + n] = f2bf(fmaxf(a2c[rt][i] + bb, 0.f));
            }
    }
    __syncthreads();

    // ---- layer3 ----
    if (t < 32) {
        float a3 = LD<F32>(b3, 0);
        #pragma unroll
        for (int k = 0; k < 32; ++k)
            a3 += bf2f(s_h2[t * SH2 + k]) * LD<F32>(W3, k);
        if (F32) ((float*)outv)[node0 + t] = a3;
        else     ((u16*)outv)[node0 + t]   = f2bf(a3);
    }
}

__launch_bounds__(512)
__global__ void k_fused(const int* __restrict__ row_start, const int* __restrict__ elist,
                        const void* __restrict__ xv,
                        const void* __restrict__ Wl, const void* __restrict__ bl,
                        const void* __restrict__ Wr,
                        const void* __restrict__ W1, const void* __restrict__ b1,
                        const void* __restrict__ W2, const void* __restrict__ b2,
                        const void* __restrict__ W3, const void* __restrict__ b3,
                        void* __restrict__ outv, const int* __restrict__ flags) {
    __shared__ __align__(16) char smem[52224];
    __shared__ int s_rs[33];
    if (flags[0])
        fused_body<1>(row_start, elist, xv, Wl, bl, Wr, W1, b1, W2, b2, W3, b3, outv, smem, s_rs);
    else
        fused_body<0>(row_start, elist, xv, Wl, bl, Wr, W1, b1, W2, b2, W3, b3, outv, smem, s_rs);
}

extern "C" void kernel_launch(void* const* d_in, const int* in_sizes, int n_in,
                              void* d_out, int out_size, void* d_ws, size_t ws_size,
                              hipStream_t stream) {
    const u16* x  = (const u16*)d_in[0];
    const int* ei = (const int*)d_in[1];
    const void* Wl = d_in[2];
    const void* bl = d_in[3];
    const void* Wr = d_in[4];
    const void* W1 = d_in[5];
    const void* b1 = d_in[6];
    const void* W2 = d_in[7];
    const void* b2 = d_in[8];
    const void* W3 = d_in[9];
    const void* b3 = d_in[10];

    // ws (ints): [flags 2][pad 256][cnt_i NN][cursor NN][row_start NN+1][elist NE]
    int* flags     = (int*)d_ws;
    int* cnt_i     = flags + 256;
    int* cursor    = cnt_i + NN;
    int* row_start = cursor + NN;
    int* elist     = row_start + NN + 1;

    k_prep<<<(2 * NN + 255) / 256, 256, 0, stream>>>(x, ei, flags, cnt_i, 2 * NN);
    k_hist<<<(NE + 255) / 256, 256, 0, stream>>>(ei, cnt_i, flags);
    k_scan<<<1, 1024, 0, stream>>>(cnt_i, row_start);
    k_fill<<<(NE + 255) / 256, 256, 0, stream>>>(ei, row_start, cursor, elist, flags);
    k_fused<<<NN / 32, 512, 0, stream>>>(row_start, elist, (const void*)x, Wl, bl, Wr,
                                         W1, b1, W2, b2, W3, b3, d_out, flags);
}